// Round 9
// baseline (473.501 us; speedup 1.0000x reference)
//
#include <hip/hip_runtime.h>

typedef unsigned short u16;
typedef unsigned int   u32;
typedef __attribute__((ext_vector_type(4))) float f32x4;
typedef __attribute__((ext_vector_type(8))) short short8;
typedef __attribute__((ext_vector_type(4))) unsigned short u16x4;

#define DEV __device__ __forceinline__
#define AS1 __attribute__((address_space(1)))
#define AS3 __attribute__((address_space(3)))
#define SB  __builtin_amdgcn_sched_barrier(0)
#define BAR __builtin_amdgcn_s_barrier()

DEV float bf2f(u16 u){ return __uint_as_float(((u32)u)<<16); }
DEV u16 f2bf(float f){ u32 u=__float_as_uint(f); return (u16)((u + 0x7fffu + ((u>>16)&1u))>>16); }
DEV void g2lds16(const void* g, void* l){
  __builtin_amdgcn_global_load_lds((const AS1 void*)g, (AS3 void*)l, 16, 0, 0);
}

// ---------------- mega prep: weight transposes + bias concat + F->bf16 + KNN ----------------
struct WtJobs {
  const float* W[14];
  u16*         WT[14];
  int K[14];
  int N[14];
  int off[15];
};
struct PrepArgs {
  WtJobs J;
  const float* qb[2][3];   // q/k/v bias sources per encoder
  float*       bq[2];      // concat dst [3072]
  const float* F; u16* Fb; long n4;
  const float* verts; unsigned char* nbr1; unsigned char* nbr2;
};

__global__ __launch_bounds__(256) void prep_kernel(PrepArgs P){
  int bid = blockIdx.x, tid = threadIdx.x;
  int nwt = P.J.off[14];
  if (bid < nwt){
    // ---- f32 [K][N] -> bf16 [N][K] tile transpose ----
    __shared__ u16 tile[32][33];
    int j = 0;
    #pragma unroll
    for (int s=1;s<14;++s) if (bid >= P.J.off[s]) j = s;
    int lb = bid - P.J.off[j];
    int K = P.J.K[j], N = P.J.N[j];
    int nx = N>>5;
    int n0 = (lb % nx)<<5, k0 = (lb / nx)<<5;
    const float* W = P.J.W[j];
    u16* WT = P.J.WT[j];
    int tx = tid&31, ty = tid>>5;                    // 32x8
    #pragma unroll
    for (int i=0;i<4;++i){
      int k = ty + i*8;
      tile[k][tx] = f2bf(W[(size_t)(k0+k)*N + n0 + tx]);
    }
    __syncthreads();
    #pragma unroll
    for (int i=0;i<4;++i){
      int n = ty + i*8;
      WT[(size_t)(n0+n)*K + k0 + tx] = tile[tx][n];
    }
  } else if (bid < nwt + 24){
    // ---- bias concat: 12 blocks per encoder ----
    int lb = bid - nwt;
    int e = lb / 12;
    int i = (lb % 12)*256 + tid;
    float v = (i < 1024) ? P.qb[e][0][i] : (i < 2048) ? P.qb[e][1][i-1024] : P.qb[e][2][i-2048];
    P.bq[e][i] = v;
  } else if (bid < nwt + 24 + 5120){
    // ---- F f32 -> bf16, x4 ----
    long i = ((long)(bid - nwt - 24)*256 + tid);
    if (i < P.n4){
      f32x4 v = *(const f32x4*)(P.F + i*4);
      u16x4 r; r.x=f2bf(v.x); r.y=f2bf(v.y); r.z=f2bf(v.z); r.w=f2bf(v.w);
      *(u16x4*)(P.Fb + i*4) = r;
    }
  } else {
    // ---- KNN: one wave per row-group ----
    __shared__ float Pv[40][3];
    __shared__ float SQ[40];
    int b = bid - nwt - 24 - 5120;
    int wave = tid>>6, lane = tid&63;
    if (tid < 40){
      float x = P.verts[((size_t)b*40+tid)*3+0];
      float y = P.verts[((size_t)b*40+tid)*3+1];
      float z = P.verts[((size_t)b*40+tid)*3+2];
      Pv[tid][0]=x; Pv[tid][1]=y; Pv[tid][2]=z;
      SQ[tid] = __fadd_rn(__fadd_rn(__fmul_rn(x,x),__fmul_rn(y,y)),__fmul_rn(z,z));
    }
    __syncthreads();
    for (int i = wave; i < 40; i += 4){
      float d = 3.0e38f;
      if (lane < 40){
        int j = lane;
        float dot = __fadd_rn(__fadd_rn(__fmul_rn(Pv[i][0],Pv[j][0]),
                                        __fmul_rn(Pv[i][1],Pv[j][1])),
                              __fmul_rn(Pv[i][2],Pv[j][2]));
        d = __fadd_rn(__fadd_rn(__fmul_rn(-2.f,dot), SQ[j]), SQ[i]);
      }
      bool taken = false;
      #pragma unroll
      for (int s=0;s<8;++s){
        float v = taken ? 3.0e38f : d;
        float m = v;
        #pragma unroll
        for (int o=32;o;o>>=1) m = fminf(m, __shfl_xor(m, o));
        unsigned long long mask = __ballot(v == m);
        int bj = __ffsll((unsigned long long)mask) - 1;   // lowest index among ties (stable)
        if (lane == bj) taken = true;
        if (lane == 0){
          if (s < 4) P.nbr1[((size_t)b*40+i)*4+s] = (unsigned char)bj;
          P.nbr2[((size_t)b*40+i)*8+s] = (unsigned char)bj;
        }
      }
    }
  }
}

// ---------------- sentinel fill (ws too small diagnostic) ----------------
__global__ __launch_bounds__(256) void fill_kernel(float* p, float v, long n){
  long i = (long)blockIdx.x*256 + threadIdx.x;
  if (i < n) p[i] = v;
}

// ---------------- grouped pointers for 2-encoder batched GEMMs ----------------
struct GemmZ { const u16* A; const u16* BT; const float* bias; void* C; };

// ---------------- 128x128 MFMA GEMM (m97 structure), grouped over blockIdx.z ----------------
template<int RELU, int OUTBF>
__global__ __launch_bounds__(256, 4) void gemm_btz(GemmZ g0, GemmZ g1,
                                                   int M, int N, int K, int lda, int ldc){
  GemmZ g = blockIdx.z ? g1 : g0;
  __shared__ u16 As[128*32];
  __shared__ u16 Bs[128*32];
  const int tid  = threadIdx.x;
  const int wave = tid>>6, lane = tid&63;
  const int wr = (wave>>1)<<6, wc = (wave&1)<<6;
  const int row0 = blockIdx.x<<7, col0 = blockIdx.y<<7;
  f32x4 acc[4][4];
  #pragma unroll
  for (int i=0;i<4;++i)
    #pragma unroll
    for (int j=0;j<4;++j) acc[i][j] = (f32x4){0.f,0.f,0.f,0.f};

  const int rL = lane>>2;
  const int ch = lane&3;
  const int fr = lane&15, fc = lane>>4;
  const short8* Asv = (const short8*)As;
  const short8* Bsv = (const short8*)Bs;

  for (int kt=0; kt<K; kt+=32){
    #pragma unroll
    for (int c=0;c<2;++c){
      int lo = c*4096 + wave*1024;
      int r  = c*64 + wave*16 + rL;
      int kk = ((ch ^ ((r>>1)&3))<<3);         // pre-swizzled global source chunk
      g2lds16(g.A  + (size_t)(row0+r)*lda + kt + kk, (char*)As + lo);
      g2lds16(g.BT + (size_t)(col0+r)*K   + kt + kk, (char*)Bs + lo);
    }
    __syncthreads();
    short8 a[4], b[4];
    #pragma unroll
    for (int i=0;i<4;++i){
      int rowA = wr + i*16 + fr;
      int rowB = wc + i*16 + fr;
      a[i] = Asv[rowA*4 + (fc ^ ((rowA>>1)&3))];
      b[i] = Bsv[rowB*4 + (fc ^ ((rowB>>1)&3))];
    }
    #pragma unroll
    for (int i=0;i<4;++i)
      #pragma unroll
      for (int j=0;j<4;++j)
        acc[i][j] = __builtin_amdgcn_mfma_f32_16x16x32_bf16(a[i], b[j], acc[i][j], 0,0,0);
    __syncthreads();
  }
  #pragma unroll
  for (int i=0;i<4;++i){
    int mrow = row0 + wr + i*16 + fc*4;
    #pragma unroll
    for (int j=0;j<4;++j){
      int ncol = col0 + wc + j*16 + fr;
      float bv = g.bias[ncol];
      #pragma unroll
      for (int r=0;r<4;++r){
        float v = acc[i][j][r] + bv;
        if (RELU) v = v > 0.f ? v : 0.f;
        if (OUTBF) ((u16*)g.C)[(size_t)(mrow+r)*ldc + ncol] = f2bf(v);
        else       ((float*)g.C)[(size_t)(mrow+r)*ldc + ncol] = v;
      }
    }
  }
}

// ---------------- 256x256 pipelined GEMM: ring-4 LDS, BK=32, grouped over z ----------------
DEV void stage32(const u16* __restrict__ gbase, int ldg, u16* __restrict__ buf,
                 int kt, int wave, int lane){
  int srw = wave*16 + (lane>>2);
  int scl = (lane&3) ^ ((srw>>1)&3);
  const u16* src = gbase + (size_t)srw*ldg + kt + scl*8;
  char* dst = (char*)buf + wave*1024;            // wave-uniform; HW adds lane*16
  g2lds16(src, dst);
  g2lds16(src + (size_t)128*ldg, dst + 8192);
}

template<int RELU>
__global__ __launch_bounds__(512, 1) void gemm256pz(GemmZ g0, GemmZ g1,
                                                    int M, int N, int K, int lda, int ldc){
  GemmZ g = blockIdx.z ? g1 : g0;
  __shared__ u16 As[4][256*32];
  __shared__ u16 Bs[4][256*32];
  const int tid  = threadIdx.x;
  const int wave = tid>>6, lane = tid&63;
  const int wm = wave>>2, wn = wave&3;
  const int fr = lane&15, fc = lane>>4;
  const int row0 = blockIdx.x<<8, col0 = blockIdx.y<<8;
  const int NT = K>>5;                            // requires NT >= 4
  const u16* Ag = g.A  + (size_t)row0*lda;
  const u16* Bg = g.BT + (size_t)col0*K;

  f32x4 acc[8][4];
  #pragma unroll
  for (int i=0;i<8;++i)
    #pragma unroll
    for (int j=0;j<4;++j) acc[i][j] = (f32x4){0.f,0.f,0.f,0.f};

  stage32(Ag, lda, As[0], 0,  wave, lane);  stage32(Bg, K, Bs[0], 0,  wave, lane);
  stage32(Ag, lda, As[1], 32, wave, lane);  stage32(Bg, K, Bs[1], 32, wave, lane);
  stage32(Ag, lda, As[2], 64, wave, lane);  stage32(Bg, K, Bs[2], 64, wave, lane);
  asm volatile("s_waitcnt vmcnt(8)" ::: "memory");
  SB; BAR; SB;

  for (int t = 0; t < NT; ++t){
    const int cur = t&3, nx3 = (t+3)&3;
    const short8* AV = (const short8*)As[cur];
    const short8* BV = (const short8*)Bs[cur];
    short8 a[4], b[4];
    #pragma unroll
    for (int nf=0;nf<4;++nf){ int rr = wn*64 + nf*16 + fr; b[nf] = BV[rr*4 + (fc ^ ((rr>>1)&3))]; }
    #pragma unroll
    for (int mf=0;mf<4;++mf){ int rr = wm*128 + mf*16 + fr; a[mf] = AV[rr*4 + (fc ^ ((rr>>1)&3))]; }
    if (t+3 < NT) stage32(Ag, lda, As[nx3], (t+3)<<5, wave, lane);
    SB; BAR; SB;
    __builtin_amdgcn_s_setprio(1);
    #pragma unroll
    for (int mf=0;mf<4;++mf)
      #pragma unroll
      for (int nf=0;nf<4;++nf)
        acc[mf][nf] = __builtin_amdgcn_mfma_f32_16x16x32_bf16(a[mf], b[nf], acc[mf][nf], 0,0,0);
    __builtin_amdgcn_s_setprio(0);
    SB; BAR; SB;
    #pragma unroll
    for (int mf=0;mf<4;++mf){ int rr = wm*128 + (mf+4)*16 + fr; a[mf] = AV[rr*4 + (fc ^ ((rr>>1)&3))]; }
    if (t+3 < NT) stage32(Bg, K, Bs[nx3], (t+3)<<5, wave, lane);
    {
      int rem = NT - t - 1;
      if (rem >= 3)      asm volatile("s_waitcnt vmcnt(8)" ::: "memory");
      else if (rem == 2) asm volatile("s_waitcnt vmcnt(4)" ::: "memory");
      else if (rem == 1) asm volatile("s_waitcnt vmcnt(0)" ::: "memory");
    }
    SB; BAR; SB;
    __builtin_amdgcn_s_setprio(1);
    #pragma unroll
    for (int mf=0;mf<4;++mf)
      #pragma unroll
      for (int nf=0;nf<4;++nf)
        acc[mf+4][nf] = __builtin_amdgcn_mfma_f32_16x16x32_bf16(a[mf], b[nf], acc[mf+4][nf], 0,0,0);
    __builtin_amdgcn_s_setprio(0);
    SB; BAR; SB;
  }

  #pragma unroll
  for (int i=0;i<8;++i){
    int mrow = row0 + wm*128 + i*16 + fc*4;
    #pragma unroll
    for (int j=0;j<4;++j){
      int ncol = col0 + wn*64 + j*16 + fr;
      float bv = g.bias[ncol];
      #pragma unroll
      for (int r=0;r<4;++r){
        float v = acc[i][j][r] + bv;
        if (RELU) v = v > 0.f ? v : 0.f;
        ((u16*)g.C)[(size_t)(mrow+r)*ldc + ncol] = f2bf(v);
      }
    }
  }
}

// ---------------- sparse masked attention: grouped over z (2 encoders), K/V in LDS ----------
struct AttnZ { const u16* QKV; const unsigned char* nbr; u16* O; };

template<int KNB>
DEV void attn_body(const u16* __restrict__ QKV, const unsigned char* __restrict__ nbr,
                   u16* __restrict__ O, u16 KV[2][40*256]){
  int b = blockIdx.x>>2, h = blockIdx.x&3;
  int tid = threadIdx.x, wave = tid>>6, lane = tid&63;
  const size_t rowb = (size_t)b*40;
  for (int c = tid; c < 1280; c += 256){          // 40 rows x 32 chunks of 16B
    int row = c >> 5, col = (c & 31) << 3;
    size_t src = (rowb+row)*3072 + h*256 + col;
    *(short8*)&KV[0][row*256+col] = *(const short8*)(QKV + src + 1024);
    *(short8*)&KV[1][row*256+col] = *(const short8*)(QKV + src + 2048);
  }
  __syncthreads();
  for (int i = wave; i < 40; i += 4){
    int js[KNB];
    if (KNB == 4){
      u32 p = *(const u32*)(nbr + (rowb+i)*4);
      js[0]=p&255; js[1]=(p>>8)&255; js[2]=(p>>16)&255; js[3]=(p>>24)&255;
    } else {
      u32 p0 = *(const u32*)(nbr + (rowb+i)*8);
      u32 p1 = *(const u32*)(nbr + (rowb+i)*8 + 4);
      js[0]=p0&255; js[1]=(p0>>8)&255; js[2]=(p0>>16)&255; js[3]=(p0>>24)&255;
      js[4]=p1&255; js[5]=(p1>>8)&255; js[6]=(p1>>16)&255; js[7]=(p1>>24)&255;
    }
    u16x4 qv = *(const u16x4*)(QKV + (rowb+i)*3072 + h*256 + lane*4);
    float q0=bf2f(qv.x), q1=bf2f(qv.y), q2=bf2f(qv.z), q3=bf2f(qv.w);
    float s[KNB];
    #pragma unroll
    for (int jj=0;jj<KNB;++jj){
      u16x4 kv = *(const u16x4*)&KV[0][js[jj]*256 + lane*4];
      s[jj] = q0*bf2f(kv.x) + q1*bf2f(kv.y) + q2*bf2f(kv.z) + q3*bf2f(kv.w);
    }
    #pragma unroll
    for (int jj=0;jj<KNB;++jj){
      #pragma unroll
      for (int o=32;o;o>>=1) s[jj] += __shfl_xor(s[jj], o);
      s[jj] *= 0.0625f;                       // 1/sqrt(256)
    }
    float m = s[0];
    #pragma unroll
    for (int jj=1;jj<KNB;++jj) m = fmaxf(m, s[jj]);
    float sum = 0.f;
    #pragma unroll
    for (int jj=0;jj<KNB;++jj){ s[jj] = expf(s[jj]-m); sum += s[jj]; }
    float inv = 1.f/sum;
    float o0=0.f,o1=0.f,o2=0.f,o3=0.f;
    #pragma unroll
    for (int jj=0;jj<KNB;++jj){
      float w = s[jj]*inv;
      u16x4 vv = *(const u16x4*)&KV[1][js[jj]*256 + lane*4];
      o0 += w*bf2f(vv.x); o1 += w*bf2f(vv.y); o2 += w*bf2f(vv.z); o3 += w*bf2f(vv.w);
    }
    u16x4 r; r.x=f2bf(o0); r.y=f2bf(o1); r.z=f2bf(o2); r.w=f2bf(o3);
    *(u16x4*)(O + (rowb+i)*2048 + h*256 + lane*4) = r;
  }
}

__global__ __launch_bounds__(256) void attn2_kernel(AttnZ a0, AttnZ a1){
  __shared__ u16 KV[2][40*256];
  if (blockIdx.z == 0) attn_body<4>(a0.QKV, a0.nbr, a0.O, KV);
  else                 attn_body<8>(a1.QKV, a1.nbr, a1.O, KV);
}

// ---------------- residual + LayerNorm, grouped over blockIdx.y (2 encoders) ----------------
struct LnJob { const float* resf; const u16* delta; const float* g; const float* be;
               u16* outb; float* outf; };

DEV float blockReduce(float v, float* red){
  #pragma unroll
  for (int o=32;o;o>>=1) v += __shfl_xor(v, o);
  int lane = threadIdx.x&63, w = threadIdx.x>>6;
  if (lane==0) red[w] = v;
  __syncthreads();
  float t = red[0]+red[1]+red[2]+red[3];
  __syncthreads();
  return t;
}

__global__ __launch_bounds__(256) void ln2_kernel(LnJob j0, LnJob j1, int rstride){
  __shared__ float red[4];
  LnJob j = blockIdx.y ? j1 : j0;
  int row = blockIdx.x, tid = threadIdx.x;
  size_t ibr = (size_t)row*rstride + tid*2;
  size_t ibd = (size_t)row*1024 + tid*2;
  float2 xr = *(const float2*)(j.resf+ibr);
  u32 dp = *(const u32*)(j.delta+ibd);
  float x0 = xr.x + bf2f((u16)(dp&0xffffu));
  float x1 = xr.y + bf2f((u16)(dp>>16));
  float s = blockReduce(x0+x1, red);
  float mean = s*(1.f/512.f);
  float d0 = x0-mean, d1 = x1-mean;
  float q = blockReduce(d0*d0+d1*d1, red);
  float inv = 1.f/sqrtf(q*(1.f/512.f)+1e-5f);
  float2 gg = *(const float2*)(j.g+tid*2);
  float2 bb = *(const float2*)(j.be+tid*2);
  float r0 = d0*inv*gg.x + bb.x;
  float r1 = d1*inv*gg.y + bb.y;
  *(u32*)(j.outb + ibd) = ((u32)f2bf(r1)<<16) | (u32)f2bf(r0);
  if (j.outf) *(float2*)(j.outf + ibd) = make_float2(r0,r1);
}

// ---------------- BatchNorm (training stats over 10240 rows) ----------------
__global__ __launch_bounds__(512) void bn_part(const float* __restrict__ y,
                                               float* __restrict__ psum, float* __restrict__ psq){
  int c = threadIdx.x, blk = blockIdx.x;   // 256 blocks x 512 threads
  float s = 0.f, q = 0.f;
  for (int r = blk; r < 10240; r += 256){
    float v = y[(size_t)r*512 + c];
    s += v; q += v*v;
  }
  psum[blk*512+c] = s; psq[blk*512+c] = q;
}

__global__ __launch_bounds__(512) void bn_fin(const float* __restrict__ psum,
                                              const float* __restrict__ psq,
                                              const float* __restrict__ g,
                                              const float* __restrict__ b,
                                              float* __restrict__ scale, float* __restrict__ shift){
  int c = threadIdx.x;
  float s = 0.f, q = 0.f;
  for (int k=0;k<256;++k){ s += psum[k*512+c]; q += psq[k*512+c]; }
  float m = s*(1.f/10240.f);
  float var = q*(1.f/10240.f) - m*m;
  float sc = g[c]/sqrtf(var + 1e-5f);
  scale[c] = sc; shift[c] = b[c] - m*sc;
}

__global__ __launch_bounds__(256) void bn_apply(const float* __restrict__ y,
                                                const float* __restrict__ scale,
                                                const float* __restrict__ shift,
                                                u16* __restrict__ out){
  long i4 = ((long)blockIdx.x*256 + threadIdx.x)*4;
  if (i4 < (long)10240*512){
    int c = (int)(i4 & 511);
    f32x4 v  = *(const f32x4*)(y+i4);
    f32x4 sc = *(const f32x4*)(scale+c);
    f32x4 sh = *(const f32x4*)(shift+c);
    f32x4 r;
    #pragma unroll
    for (int k=0;k<4;++k){
      float t = v[k]*sc[k] + sh[k];
      r[k] = t > 0.f ? t : 0.2f*t;             // LeakyReLU(0.2)
    }
    u16x4 o; o.x=f2bf(r[0]); o.y=f2bf(r[1]); o.z=f2bf(r[2]); o.w=f2bf(r[3]);
    *(u16x4*)(out+i4) = o;
  }
}

extern "C" void kernel_launch(void* const* d_in, const int* in_sizes, int n_in,
                              void* d_out, int out_size, void* d_ws, size_t ws_size,
                              hipStream_t stream){
  const float* verts = (const float*)d_in[0];
  const float* F     = (const float*)d_in[1];
  const float* ew[2][16];
  for (int e=0;e<2;++e) for (int i=0;i<16;++i) ew[e][i] = (const float*)d_in[2+e*16+i];
  const float* fus_w1  = (const float*)d_in[34];
  const float* fus_b1  = (const float*)d_in[35];
  const float* fus_bng = (const float*)d_in[36];
  const float* fus_bnb = (const float*)d_in[37];
  const float* fus_w2  = (const float*)d_in[38];
  const float* fus_b2  = (const float*)d_in[39];

  const int M = 10240;
  size_t off = 0;
  auto alloc = [&](size_t bytes)->void*{
    void* p = (char*)d_ws + off; off = (off + bytes + 255) & ~(size_t)255; return p;
  };
  u16 *wtqkv[2],*wto[2],*wtw1[2],*wtw2[2];
  float* bqkv[2];
  for (int e=0;e<2;++e){
    wtqkv[e] = (u16*)alloc((size_t)3072*512*2);   // [N=3072][K=512] = q|k|v stacked
    wto[e]   = (u16*)alloc((size_t)512*1024*2);
    wtw1[e]  = (u16*)alloc((size_t)2048*512*2);
    wtw2[e]  = (u16*)alloc((size_t)512*2048*2);
    bqkv[e]  = (float*)alloc(3072*4);
  }
  u16*  wtf1 = (u16*)alloc((size_t)512*1024*2);   // [N=512][K=1024]
  u16*  wtf2 = (u16*)alloc((size_t)512*512*2);
  u16*  Fb   = (u16*)alloc((size_t)M*512*2);
  u16*  QKVb = (u16*)alloc((size_t)M*3072*2);     // 60 MB, encoder-0
  u16*  H1   = (u16*)alloc((size_t)M*4096*2);     // both encoders' FFN1 out [M][4096]
  u16*  PF   = (u16*)alloc((size_t)M*1024*2);     // both encoders' delta (bf16) [M][1024]
  u16*  X1b  = (u16*)alloc((size_t)M*1024*2);     // both encoders' LN1 out bf16 [M][1024]
  u16*  YC   = (u16*)alloc((size_t)M*1024*2);     // concat LN2 out [M][1024]
  unsigned char* nbr1 = (unsigned char*)alloc(256*40*4);
  unsigned char* nbr2 = (unsigned char*)alloc(256*40*8);
  float* psum = (float*)alloc(256*512*4);
  float* psq  = (float*)alloc(256*512*4);
  float* bnsc = (float*)alloc(512*4);
  float* bnsh = (float*)alloc(512*4);
  // time-disjoint aliases:
  u16*   QKV2 = PF;                               // [M][3072] enc-1 QKV over PF+X1b+YC (=60MB
                                                  //  exactly); dead before O-proj writes PF
  u16*   OB  = H1;                                // [M][2048] attn out; dead before FFN1 writes H1
  float* X1f = (float*)QKVb;                      // [M][1024] LN1 f32; QKVb dead after attn
  float* Y1  = (float*)QKVb;                      // [M][512] fusion f32 out; X1f dead after LN2
  u16*   Y2  = (u16*)((char*)QKVb + (size_t)24*1024*1024);  // BN out, disjoint from Y1

  if (off > ws_size){      // ws too small: distinguishable sentinel
    long n = out_size;
    fill_kernel<<<(unsigned)((n+255)/256),256,0,stream>>>((float*)d_out, 12345.0f, n);
    return;
  }

  // ---- mega prep: transposes + bias concat + F->bf16 + KNN in one launch ----
  PrepArgs P;
  int nb = 0, ji = 0;
  auto addjob = [&](const float* W, u16* WT, int K, int N){
    P.J.W[ji]=W; P.J.WT[ji]=WT; P.J.K[ji]=K; P.J.N[ji]=N; P.J.off[ji]=nb;
    nb += (N>>5)*(K>>5); ++ji;
  };
  for (int e=0;e<2;++e){
    addjob(ew[e][0],  wtqkv[e],                    512, 1024);
    addjob(ew[e][2],  wtqkv[e]+(size_t)1024*512,   512, 1024);
    addjob(ew[e][4],  wtqkv[e]+(size_t)2048*512,   512, 1024);
    addjob(ew[e][6],  wto[e],  1024, 512);
    addjob(ew[e][10], wtw1[e], 512, 2048);
    addjob(ew[e][12], wtw2[e], 2048, 512);
  }
  addjob(fus_w1, wtf1, 1024, 512);
  addjob(fus_w2, wtf2, 512, 512);
  P.J.off[14] = nb;
  for (int e=0;e<2;++e){
    P.qb[e][0]=ew[e][1]; P.qb[e][1]=ew[e][3]; P.qb[e][2]=ew[e][5]; P.bq[e]=bqkv[e];
  }
  P.F = F; P.Fb = Fb; P.n4 = (long)M*512/4;
  P.verts = verts; P.nbr1 = nbr1; P.nbr2 = nbr2;
  prep_kernel<<<nb + 24 + 5120 + 256, 256, 0, stream>>>(P);

  // ---- QKV for BOTH encoders in one launch; then both attentions in one launch ----
  {
    GemmZ q0{Fb, wtqkv[0], bqkv[0], QKVb};
    GemmZ q1{Fb, wtqkv[1], bqkv[1], QKV2};
    gemm256pz<0><<<dim3(40,12,2),512,0,stream>>>(q0, q1, M, 3072, 512, 512, 3072);
  }
  {
    AttnZ a0{QKVb, nbr1, OB};
    AttnZ a1{QKV2, nbr2, OB + 1024};
    attn2_kernel<<<dim3(1024,1,2),256,0,stream>>>(a0, a1);
  }

  // ---- grouped 2-encoder stages ----
  {
    GemmZ o0{OB,        wto[0], ew[0][7], PF};
    GemmZ o1{OB + 1024, wto[1], ew[1][7], PF + 512};
    gemm_btz<0,1><<<dim3(80,4,2),256,0,stream>>>(o0, o1, M, 512, 1024, 2048, 1024);
  }
  {
    LnJob a{F, PF,       ew[0][8], ew[0][9], X1b,       X1f};
    LnJob b{F, PF + 512, ew[1][8], ew[1][9], X1b + 512, X1f + 512};
    ln2_kernel<<<dim3(M,2),256,0,stream>>>(a, b, 512);
  }
  {
    GemmZ f0{X1b,       wtw1[0], ew[0][11], H1};
    GemmZ f1{X1b + 512, wtw1[1], ew[1][11], H1 + 2048};
    gemm256pz<1><<<dim3(40,8,2),512,0,stream>>>(f0, f1, M, 2048, 512, 1024, 4096);
  }
  {
    GemmZ f0{H1,        wtw2[0], ew[0][13], PF};
    GemmZ f1{H1 + 2048, wtw2[1], ew[1][13], PF + 512};
    gemm_btz<0,1><<<dim3(80,4,2),256,0,stream>>>(f0, f1, M, 512, 2048, 4096, 1024);
  }
  {
    LnJob a{X1f,       PF,       ew[0][14], ew[0][15], YC,       nullptr};
    LnJob b{X1f + 512, PF + 512, ew[1][14], ew[1][15], YC + 512, nullptr};
    ln2_kernel<<<dim3(M,2),256,0,stream>>>(a, b, 1024);
  }

  // ---- fusion ----
  {
    GemmZ fz{YC, wtf1, fus_b1, Y1};
    gemm_btz<0,0><<<dim3(80,4,1),256,0,stream>>>(fz, fz, M, 512, 1024, 1024, 512);
  }
  bn_part<<<256,512,0,stream>>>(Y1, psum, psq);
  bn_fin<<<1,512,0,stream>>>(psum, psq, fus_bng, fus_bnb, bnsc, bnsh);
  bn_apply<<<5120,256,0,stream>>>(Y1, bnsc, bnsh, Y2);
  {
    GemmZ fz{Y2, wtf2, fus_b2, d_out};
    gemm_btz<0,0><<<dim3(80,4,1),256,0,stream>>>(fz, fz, M, 512, 512, 512, 512);
  }
}

// Round 10
// 450.301 us; speedup vs baseline: 1.0515x; 1.0515x over previous
//
#include <hip/hip_runtime.h>

typedef unsigned short u16;
typedef unsigned int   u32;
typedef __attribute__((ext_vector_type(4))) float f32x4;
typedef __attribute__((ext_vector_type(8))) short short8;
typedef __attribute__((ext_vector_type(4))) unsigned short u16x4;

#define DEV __device__ __forceinline__
#define AS1 __attribute__((address_space(1)))
#define AS3 __attribute__((address_space(3)))
#define SB  __builtin_amdgcn_sched_barrier(0)
#define BAR __builtin_amdgcn_s_barrier()

DEV float bf2f(u16 u){ return __uint_as_float(((u32)u)<<16); }
DEV u16 f2bf(float f){ u32 u=__float_as_uint(f); return (u16)((u + 0x7fffu + ((u>>16)&1u))>>16); }
DEV void g2lds16(const void* g, void* l){
  __builtin_amdgcn_global_load_lds((const AS1 void*)g, (AS3 void*)l, 16, 0, 0);
}

// ---------------- batched f32 [K][N] -> bf16 [N][K] transposes (one launch) ----------------
struct WtJobs {
  const float* W[14];
  u16*         WT[14];
  int K[14];
  int N[14];
  int off[15];
};

__global__ __launch_bounds__(256) void wtb_kernel(WtJobs J){
  __shared__ u16 tile[32][33];
  int bid = blockIdx.x;
  int j = 0;
  #pragma unroll
  for (int s=1;s<14;++s) if (bid >= J.off[s]) j = s;
  int lb = bid - J.off[j];
  int K = J.K[j], N = J.N[j];
  int nx = N>>5;
  int n0 = (lb % nx)<<5, k0 = (lb / nx)<<5;
  const float* W = J.W[j];
  u16* WT = J.WT[j];
  int tx = threadIdx.x, ty = threadIdx.y;            // (32,8)
  #pragma unroll
  for (int i=0;i<4;++i){
    int k = ty + i*8;
    tile[k][tx] = f2bf(W[(size_t)(k0+k)*N + n0 + tx]);
  }
  __syncthreads();
  #pragma unroll
  for (int i=0;i<4;++i){
    int n = ty + i*8;
    WT[(size_t)(n0+n)*K + k0 + tx] = tile[tx][n];
  }
}

// ---------------- f32 -> bf16 elementwise (x4 vectorized) ----------------
__global__ __launch_bounds__(256) void cvt_kernel(const float* __restrict__ in,
                                                  u16* __restrict__ out, long n4){
  long i = ((long)blockIdx.x*256 + threadIdx.x);
  if (i < n4){
    f32x4 v = *(const f32x4*)(in + i*4);
    u16x4 r; r.x=f2bf(v.x); r.y=f2bf(v.y); r.z=f2bf(v.z); r.w=f2bf(v.w);
    *(u16x4*)(out + i*4) = r;
  }
}

// ---------------- concat q/k/v bias vectors for both encoders (24 blocks) ----------------
__global__ __launch_bounds__(256) void catb2_kernel(const float* a0, const float* b0, const float* c0, float* d0,
                                                    const float* a1, const float* b1, const float* c1, float* d1){
  int lb = blockIdx.x;
  int e = lb / 12;
  int i = (lb % 12)*256 + threadIdx.x;
  const float* a = e ? a1 : a0;  const float* b = e ? b1 : b0;
  const float* c = e ? c1 : c0;  float* d = e ? d1 : d0;
  float v = (i < 1024) ? a[i] : (i < 2048) ? b[i-1024] : c[i-2048];
  d[i] = v;
}

// ---------------- sentinel fill (ws too small diagnostic) ----------------
__global__ __launch_bounds__(256) void fill_kernel(float* p, float v, long n){
  long i = (long)blockIdx.x*256 + threadIdx.x;
  if (i < n) p[i] = v;
}

// ---------------- KNN: one wave per (batch,row), d per-lane in registers ----------------
__global__ __launch_bounds__(256) void knn_kernel(const float* __restrict__ verts,
                                                  unsigned char* __restrict__ nbr1,
                                                  unsigned char* __restrict__ nbr2){
  __shared__ float P[40][3];
  __shared__ float SQ[40];
  int b = blockIdx.x, tid = threadIdx.x, wave = tid>>6, lane = tid&63;
  if (tid < 40){
    float x = verts[((size_t)b*40+tid)*3+0];
    float y = verts[((size_t)b*40+tid)*3+1];
    float z = verts[((size_t)b*40+tid)*3+2];
    P[tid][0]=x; P[tid][1]=y; P[tid][2]=z;
    SQ[tid] = __fadd_rn(__fadd_rn(__fmul_rn(x,x),__fmul_rn(y,y)),__fmul_rn(z,z));
  }
  __syncthreads();
  for (int i = wave; i < 40; i += 4){
    float d = 3.0e38f;
    if (lane < 40){
      int j = lane;
      float dot = __fadd_rn(__fadd_rn(__fmul_rn(P[i][0],P[j][0]),
                                      __fmul_rn(P[i][1],P[j][1])),
                            __fmul_rn(P[i][2],P[j][2]));
      d = __fadd_rn(__fadd_rn(__fmul_rn(-2.f,dot), SQ[j]), SQ[i]);
    }
    bool taken = false;
    #pragma unroll
    for (int s=0;s<8;++s){
      float v = taken ? 3.0e38f : d;
      float m = v;
      #pragma unroll
      for (int o=32;o;o>>=1) m = fminf(m, __shfl_xor(m, o));
      unsigned long long mask = __ballot(v == m);
      int bj = __ffsll((unsigned long long)mask) - 1;   // lowest index among ties (stable)
      if (lane == bj) taken = true;
      if (lane == 0){
        if (s < 4) nbr1[((size_t)b*40+i)*4+s] = (unsigned char)bj;
        nbr2[((size_t)b*40+i)*8+s] = (unsigned char)bj;
      }
    }
  }
}

// ---------------- grouped pointers for 2-encoder batched GEMMs ----------------
struct GemmZ { const u16* A; const u16* BT; const float* bias; void* C; };

// ---------------- 128x128 MFMA GEMM (m97 structure), grouped over blockIdx.z ----------------
template<int RELU, int OUTBF>
__global__ __launch_bounds__(256, 4) void gemm_btz(GemmZ g0, GemmZ g1,
                                                   int M, int N, int K, int lda, int ldc){
  GemmZ g = blockIdx.z ? g1 : g0;
  __shared__ u16 As[128*32];
  __shared__ u16 Bs[128*32];
  const int tid  = threadIdx.x;
  const int wave = tid>>6, lane = tid&63;
  const int wr = (wave>>1)<<6, wc = (wave&1)<<6;
  const int row0 = blockIdx.x<<7, col0 = blockIdx.y<<7;
  f32x4 acc[4][4];
  #pragma unroll
  for (int i=0;i<4;++i)
    #pragma unroll
    for (int j=0;j<4;++j) acc[i][j] = (f32x4){0.f,0.f,0.f,0.f};

  const int rL = lane>>2;
  const int ch = lane&3;
  const int fr = lane&15, fc = lane>>4;
  const short8* Asv = (const short8*)As;
  const short8* Bsv = (const short8*)Bs;

  for (int kt=0; kt<K; kt+=32){
    #pragma unroll
    for (int c=0;c<2;++c){
      int lo = c*4096 + wave*1024;
      int r  = c*64 + wave*16 + rL;
      int kk = ((ch ^ ((r>>1)&3))<<3);         // pre-swizzled global source chunk
      g2lds16(g.A  + (size_t)(row0+r)*lda + kt + kk, (char*)As + lo);
      g2lds16(g.BT + (size_t)(col0+r)*K   + kt + kk, (char*)Bs + lo);
    }
    __syncthreads();
    short8 a[4], b[4];
    #pragma unroll
    for (int i=0;i<4;++i){
      int rowA = wr + i*16 + fr;
      int rowB = wc + i*16 + fr;
      a[i] = Asv[rowA*4 + (fc ^ ((rowA>>1)&3))];
      b[i] = Bsv[rowB*4 + (fc ^ ((rowB>>1)&3))];
    }
    #pragma unroll
    for (int i=0;i<4;++i)
      #pragma unroll
      for (int j=0;j<4;++j)
        acc[i][j] = __builtin_amdgcn_mfma_f32_16x16x32_bf16(a[i], b[j], acc[i][j], 0,0,0);
    __syncthreads();
  }
  #pragma unroll
  for (int i=0;i<4;++i){
    int mrow = row0 + wr + i*16 + fc*4;
    #pragma unroll
    for (int j=0;j<4;++j){
      int ncol = col0 + wc + j*16 + fr;
      float bv = g.bias[ncol];
      #pragma unroll
      for (int r=0;r<4;++r){
        float v = acc[i][j][r] + bv;
        if (RELU) v = v > 0.f ? v : 0.f;
        if (OUTBF) ((u16*)g.C)[(size_t)(mrow+r)*ldc + ncol] = f2bf(v);
        else       ((float*)g.C)[(size_t)(mrow+r)*ldc + ncol] = v;
      }
    }
  }
}

// ---------------- 256x256 pipelined GEMM: ring-4 LDS, BK=32, grouped over z ----------------
DEV void stage32(const u16* __restrict__ gbase, int ldg, u16* __restrict__ buf,
                 int kt, int wave, int lane){
  int srw = wave*16 + (lane>>2);
  int scl = (lane&3) ^ ((srw>>1)&3);
  const u16* src = gbase + (size_t)srw*ldg + kt + scl*8;
  char* dst = (char*)buf + wave*1024;            // wave-uniform; HW adds lane*16
  g2lds16(src, dst);
  g2lds16(src + (size_t)128*ldg, dst + 8192);
}

template<int RELU>
__global__ __launch_bounds__(512, 1) void gemm256pz(GemmZ g0, GemmZ g1,
                                                    int M, int N, int K, int lda, int ldc){
  GemmZ g = blockIdx.z ? g1 : g0;
  __shared__ u16 As[4][256*32];
  __shared__ u16 Bs[4][256*32];
  const int tid  = threadIdx.x;
  const int wave = tid>>6, lane = tid&63;
  const int wm = wave>>2, wn = wave&3;
  const int fr = lane&15, fc = lane>>4;
  const int row0 = blockIdx.x<<8, col0 = blockIdx.y<<8;
  const int NT = K>>5;                            // requires NT >= 4
  const u16* Ag = g.A  + (size_t)row0*lda;
  const u16* Bg = g.BT + (size_t)col0*K;

  f32x4 acc[8][4];
  #pragma unroll
  for (int i=0;i<8;++i)
    #pragma unroll
    for (int j=0;j<4;++j) acc[i][j] = (f32x4){0.f,0.f,0.f,0.f};

  stage32(Ag, lda, As[0], 0,  wave, lane);  stage32(Bg, K, Bs[0], 0,  wave, lane);
  stage32(Ag, lda, As[1], 32, wave, lane);  stage32(Bg, K, Bs[1], 32, wave, lane);
  stage32(Ag, lda, As[2], 64, wave, lane);  stage32(Bg, K, Bs[2], 64, wave, lane);
  asm volatile("s_waitcnt vmcnt(8)" ::: "memory");
  SB; BAR; SB;

  for (int t = 0; t < NT; ++t){
    const int cur = t&3, nx3 = (t+3)&3;
    const short8* AV = (const short8*)As[cur];
    const short8* BV = (const short8*)Bs[cur];
    short8 a[4], b[4];
    #pragma unroll
    for (int nf=0;nf<4;++nf){ int rr = wn*64 + nf*16 + fr; b[nf] = BV[rr*4 + (fc ^ ((rr>>1)&3))]; }
    #pragma unroll
    for (int mf=0;mf<4;++mf){ int rr = wm*128 + mf*16 + fr; a[mf] = AV[rr*4 + (fc ^ ((rr>>1)&3))]; }
    if (t+3 < NT) stage32(Ag, lda, As[nx3], (t+3)<<5, wave, lane);
    SB; BAR; SB;
    __builtin_amdgcn_s_setprio(1);
    #pragma unroll
    for (int mf=0;mf<4;++mf)
      #pragma unroll
      for (int nf=0;nf<4;++nf)
        acc[mf][nf] = __builtin_amdgcn_mfma_f32_16x16x32_bf16(a[mf], b[nf], acc[mf][nf], 0,0,0);
    __builtin_amdgcn_s_setprio(0);
    SB; BAR; SB;
    #pragma unroll
    for (int mf=0;mf<4;++mf){ int rr = wm*128 + (mf+4)*16 + fr; a[mf] = AV[rr*4 + (fc ^ ((rr>>1)&3))]; }
    if (t+3 < NT) stage32(Bg, K, Bs[nx3], (t+3)<<5, wave, lane);
    {
      int rem = NT - t - 1;
      if (rem >= 3)      asm volatile("s_waitcnt vmcnt(8)" ::: "memory");
      else if (rem == 2) asm volatile("s_waitcnt vmcnt(4)" ::: "memory");
      else if (rem == 1) asm volatile("s_waitcnt vmcnt(0)" ::: "memory");
    }
    SB; BAR; SB;
    __builtin_amdgcn_s_setprio(1);
    #pragma unroll
    for (int mf=0;mf<4;++mf)
      #pragma unroll
      for (int nf=0;nf<4;++nf)
        acc[mf+4][nf] = __builtin_amdgcn_mfma_f32_16x16x32_bf16(a[mf], b[nf], acc[mf+4][nf], 0,0,0);
    __builtin_amdgcn_s_setprio(0);
    SB; BAR; SB;
  }

  #pragma unroll
  for (int i=0;i<8;++i){
    int mrow = row0 + wm*128 + i*16 + fc*4;
    #pragma unroll
    for (int j=0;j<4;++j){
      int ncol = col0 + wn*64 + j*16 + fr;
      float bv = g.bias[ncol];
      #pragma unroll
      for (int r=0;r<4;++r){
        float v = acc[i][j][r] + bv;
        if (RELU) v = v > 0.f ? v : 0.f;
        ((u16*)g.C)[(size_t)(mrow+r)*ldc + ncol] = f2bf(v);
      }
    }
  }
}

// ---------------- sparse masked attention: K/V staged in LDS, bf16, strided output ----------
template<int KNB>
__global__ __launch_bounds__(256) void attn_kernel(const u16* __restrict__ QKV,
                                                   const unsigned char* __restrict__ nbr,
                                                   u16* __restrict__ O, int ldo){
  __shared__ u16 KV[2][40*256];    // [0]=K rows, [1]=V rows (bf16)
  int b = blockIdx.x>>2, h = blockIdx.x&3;
  int tid = threadIdx.x, wave = tid>>6, lane = tid&63;
  const size_t rowb = (size_t)b*40;
  for (int c = tid; c < 1280; c += 256){          // 40 rows x 32 chunks of 16B
    int row = c >> 5, col = (c & 31) << 3;
    size_t src = (rowb+row)*3072 + h*256 + col;
    *(short8*)&KV[0][row*256+col] = *(const short8*)(QKV + src + 1024);
    *(short8*)&KV[1][row*256+col] = *(const short8*)(QKV + src + 2048);
  }
  __syncthreads();
  for (int i = wave; i < 40; i += 4){
    int js[KNB];
    if (KNB == 4){
      u32 p = *(const u32*)(nbr + (rowb+i)*4);
      js[0]=p&255; js[1]=(p>>8)&255; js[2]=(p>>16)&255; js[3]=(p>>24)&255;
    } else {
      u32 p0 = *(const u32*)(nbr + (rowb+i)*8);
      u32 p1 = *(const u32*)(nbr + (rowb+i)*8 + 4);
      js[0]=p0&255; js[1]=(p0>>8)&255; js[2]=(p0>>16)&255; js[3]=(p0>>24)&255;
      js[4]=p1&255; js[5]=(p1>>8)&255; js[6]=(p1>>16)&255; js[7]=(p1>>24)&255;
    }
    u16x4 qv = *(const u16x4*)(QKV + (rowb+i)*3072 + h*256 + lane*4);
    float q0=bf2f(qv.x), q1=bf2f(qv.y), q2=bf2f(qv.z), q3=bf2f(qv.w);
    float s[KNB];
    #pragma unroll
    for (int jj=0;jj<KNB;++jj){
      u16x4 kv = *(const u16x4*)&KV[0][js[jj]*256 + lane*4];
      s[jj] = q0*bf2f(kv.x) + q1*bf2f(kv.y) + q2*bf2f(kv.z) + q3*bf2f(kv.w);
    }
    #pragma unroll
    for (int jj=0;jj<KNB;++jj){
      #pragma unroll
      for (int o=32;o;o>>=1) s[jj] += __shfl_xor(s[jj], o);
      s[jj] *= 0.0625f;                       // 1/sqrt(256)
    }
    float m = s[0];
    #pragma unroll
    for (int jj=1;jj<KNB;++jj) m = fmaxf(m, s[jj]);
    float sum = 0.f;
    #pragma unroll
    for (int jj=0;jj<KNB;++jj){ s[jj] = expf(s[jj]-m); sum += s[jj]; }
    float inv = 1.f/sum;
    float o0=0.f,o1=0.f,o2=0.f,o3=0.f;
    #pragma unroll
    for (int jj=0;jj<KNB;++jj){
      float w = s[jj]*inv;
      u16x4 vv = *(const u16x4*)&KV[1][js[jj]*256 + lane*4];
      o0 += w*bf2f(vv.x); o1 += w*bf2f(vv.y); o2 += w*bf2f(vv.z); o3 += w*bf2f(vv.w);
    }
    u16x4 r; r.x=f2bf(o0); r.y=f2bf(o1); r.z=f2bf(o2); r.w=f2bf(o3);
    *(u16x4*)(O + (rowb+i)*(size_t)ldo + h*256 + lane*4) = r;
  }
}

// ---------------- residual + LayerNorm, grouped over blockIdx.y; RBF: bf16 residual ------
struct LnJob { const void* resf; const u16* delta; const float* g; const float* be; u16* outb; };

DEV float blockReduce(float v, float* red){
  #pragma unroll
  for (int o=32;o;o>>=1) v += __shfl_xor(v, o);
  int lane = threadIdx.x&63, w = threadIdx.x>>6;
  if (lane==0) red[w] = v;
  __syncthreads();
  float t = red[0]+red[1]+red[2]+red[3];
  __syncthreads();
  return t;
}

template<int RBF>
__global__ __launch_bounds__(256) void ln2_kernel(LnJob j0, LnJob j1, int rstride){
  __shared__ float red[4];
  LnJob j = blockIdx.y ? j1 : j0;
  int row = blockIdx.x, tid = threadIdx.x;
  size_t ibd = (size_t)row*1024 + tid*2;
  float x0, x1;
  if (RBF){
    u32 rp = *(const u32*)((const u16*)j.resf + (size_t)row*rstride + tid*2);
    x0 = bf2f((u16)(rp&0xffffu)); x1 = bf2f((u16)(rp>>16));
  } else {
    float2 xr = *(const float2*)((const float*)j.resf + (size_t)row*rstride + tid*2);
    x0 = xr.x; x1 = xr.y;
  }
  u32 dp = *(const u32*)(j.delta+ibd);
  x0 += bf2f((u16)(dp&0xffffu));
  x1 += bf2f((u16)(dp>>16));
  float s = blockReduce(x0+x1, red);
  float mean = s*(1.f/512.f);
  float d0 = x0-mean, d1 = x1-mean;
  float q = blockReduce(d0*d0+d1*d1, red);
  float inv = 1.f/sqrtf(q*(1.f/512.f)+1e-5f);
  float2 gg = *(const float2*)(j.g+tid*2);
  float2 bb = *(const float2*)(j.be+tid*2);
  float r0 = d0*inv*gg.x + bb.x;
  float r1 = d1*inv*gg.y + bb.y;
  *(u32*)(j.outb + ibd) = ((u32)f2bf(r1)<<16) | (u32)f2bf(r0);
}

// ---------------- BatchNorm (training stats over 10240 rows), bf16 input ----------------
__global__ __launch_bounds__(512) void bn_part(const u16* __restrict__ y,
                                               float* __restrict__ psum, float* __restrict__ psq){
  int c = threadIdx.x, blk = blockIdx.x;   // 256 blocks x 512 threads
  float s = 0.f, q = 0.f;
  for (int r = blk; r < 10240; r += 256){
    float v = bf2f(y[(size_t)r*512 + c]);
    s += v; q += v*v;
  }
  psum[blk*512+c] = s; psq[blk*512+c] = q;
}

__global__ __launch_bounds__(512) void bn_fin(const float* __restrict__ psum,
                                              const float* __restrict__ psq,
                                              const float* __restrict__ g,
                                              const float* __restrict__ b,
                                              float* __restrict__ scale, float* __restrict__ shift){
  int c = threadIdx.x;
  float s = 0.f, q = 0.f;
  for (int k=0;k<256;++k){ s += psum[k*512+c]; q += psq[k*512+c]; }
  float m = s*(1.f/10240.f);
  float var = q*(1.f/10240.f) - m*m;
  float sc = g[c]/sqrtf(var + 1e-5f);
  scale[c] = sc; shift[c] = b[c] - m*sc;
}

__global__ __launch_bounds__(256) void bn_apply(const u16* __restrict__ y,
                                                const float* __restrict__ scale,
                                                const float* __restrict__ shift,
                                                u16* __restrict__ out){
  long i4 = ((long)blockIdx.x*256 + threadIdx.x)*4;
  if (i4 < (long)10240*512){
    int c = (int)(i4 & 511);
    u16x4 v4 = *(const u16x4*)(y+i4);
    f32x4 sc = *(const f32x4*)(scale+c);
    f32x4 sh = *(const f32x4*)(shift+c);
    float vv[4] = {bf2f(v4.x), bf2f(v4.y), bf2f(v4.z), bf2f(v4.w)};
    u16x4 o;
    #pragma unroll
    for (int k=0;k<4;++k){
      float t = vv[k]*sc[k] + sh[k];
      t = t > 0.f ? t : 0.2f*t;                // LeakyReLU(0.2)
      ((u16*)&o)[k] = f2bf(t);
    }
    *(u16x4*)(out+i4) = o;
  }
}

extern "C" void kernel_launch(void* const* d_in, const int* in_sizes, int n_in,
                              void* d_out, int out_size, void* d_ws, size_t ws_size,
                              hipStream_t stream){
  const float* verts = (const float*)d_in[0];
  const float* F     = (const float*)d_in[1];
  const float* ew[2][16];
  for (int e=0;e<2;++e) for (int i=0;i<16;++i) ew[e][i] = (const float*)d_in[2+e*16+i];
  const float* fus_w1  = (const float*)d_in[34];
  const float* fus_b1  = (const float*)d_in[35];
  const float* fus_bng = (const float*)d_in[36];
  const float* fus_bnb = (const float*)d_in[37];
  const float* fus_w2  = (const float*)d_in[38];
  const float* fus_b2  = (const float*)d_in[39];

  const int M = 10240;
  size_t off = 0;
  auto alloc = [&](size_t bytes)->void*{
    void* p = (char*)d_ws + off; off = (off + bytes + 255) & ~(size_t)255; return p;
  };
  u16 *wtqkv[2],*wto[2],*wtw1[2],*wtw2[2];
  float* bqkv[2];
  for (int e=0;e<2;++e){
    wtqkv[e] = (u16*)alloc((size_t)3072*512*2);   // [N=3072][K=512] = q|k|v stacked
    wto[e]   = (u16*)alloc((size_t)512*1024*2);
    wtw1[e]  = (u16*)alloc((size_t)2048*512*2);
    wtw2[e]  = (u16*)alloc((size_t)512*2048*2);
    bqkv[e]  = (float*)alloc(3072*4);
  }
  u16*  wtf1 = (u16*)alloc((size_t)512*1024*2);   // [N=512][K=1024]
  u16*  wtf2 = (u16*)alloc((size_t)512*512*2);
  u16*  Fb   = (u16*)alloc((size_t)M*512*2);
  u16*  QKVb = (u16*)alloc((size_t)M*3072*2);     // 60 MB, encoder-0
  u16*  H1   = (u16*)alloc((size_t)M*4096*2);     // both encoders' FFN1 out [M][4096]
  u16*  PF   = (u16*)alloc((size_t)M*1024*2);     // both encoders' delta (bf16) [M][1024]
  u16*  X1b  = (u16*)alloc((size_t)M*1024*2);     // both encoders' LN1 out bf16 [M][1024]
  u16*  YC   = (u16*)alloc((size_t)M*1024*2);     // concat LN2 out [M][1024]
  unsigned char* nbr1 = (unsigned char*)alloc(256*40*4);
  unsigned char* nbr2 = (unsigned char*)alloc(256*40*8);
  float* psum = (float*)alloc(256*512*4);
  float* psq  = (float*)alloc(256*512*4);
  float* bnsc = (float*)alloc(512*4);
  float* bnsh = (float*)alloc(512*4);
  // time-disjoint aliases:
  u16*   QKV2 = PF;                               // [M][3072] enc-1 QKV over PF+X1b+YC (=60MB
                                                  //  contiguous); dead before O-proj writes PF
  u16*   OB  = H1;                                // [M][2048] attn out; dead before FFN1 writes H1
  u16*   Y1b = (u16*)QKVb;                        // [M][512] fusion bf16 out (QKVb dead post-attn)
  u16*   Y2  = (u16*)((char*)QKVb + (size_t)12*1024*1024);  // BN out, disjoint from Y1b (10 MB)

  if (off > ws_size){      // ws too small: distinguishable sentinel
    long n = out_size;
    fill_kernel<<<(unsigned)((n+255)/256),256,0,stream>>>((float*)d_out, 12345.0f, n);
    return;
  }

  // ---- prep: batched transposes, bias concat, F->bf16, KNN (separate small launches) ----
  WtJobs J;
  int nb = 0, ji = 0;
  auto addjob = [&](const float* W, u16* WT, int K, int N){
    J.W[ji]=W; J.WT[ji]=WT; J.K[ji]=K; J.N[ji]=N; J.off[ji]=nb;
    nb += (N>>5)*(K>>5); ++ji;
  };
  for (int e=0;e<2;++e){
    addjob(ew[e][0],  wtqkv[e],                    512, 1024);
    addjob(ew[e][2],  wtqkv[e]+(size_t)1024*512,   512, 1024);
    addjob(ew[e][4],  wtqkv[e]+(size_t)2048*512,   512, 1024);
    addjob(ew[e][6],  wto[e],  1024, 512);
    addjob(ew[e][10], wtw1[e], 512, 2048);
    addjob(ew[e][12], wtw2[e], 2048, 512);
  }
  addjob(fus_w1, wtf1, 1024, 512);
  addjob(fus_w2, wtf2, 512, 512);
  J.off[14] = nb;
  wtb_kernel<<<nb, dim3(32,8), 0, stream>>>(J);
  catb2_kernel<<<24,256,0,stream>>>(ew[0][1], ew[0][3], ew[0][5], bqkv[0],
                                    ew[1][1], ew[1][3], ew[1][5], bqkv[1]);
  cvt_kernel<<<5120,256,0,stream>>>(F, Fb, (long)M*512/4);
  knn_kernel<<<256,256,0,stream>>>(verts, nbr1, nbr2);

  // ---- QKV for BOTH encoders in one launch; separate attn launches ----
  {
    GemmZ q0{Fb, wtqkv[0], bqkv[0], QKVb};
    GemmZ q1{Fb, wtqkv[1], bqkv[1], QKV2};
    gemm256pz<0><<<dim3(40,12,2),512,0,stream>>>(q0, q1, M, 3072, 512, 512, 3072);
  }
  attn_kernel<4><<<1024,256,0,stream>>>(QKVb, nbr1, OB,        2048);
  attn_kernel<8><<<1024,256,0,stream>>>(QKV2, nbr2, OB + 1024, 2048);

  // ---- grouped 2-encoder stages ----
  {
    GemmZ o0{OB,        wto[0], ew[0][7], PF};
    GemmZ o1{OB + 1024, wto[1], ew[1][7], PF + 512};
    gemm_btz<0,1><<<dim3(80,4,2),256,0,stream>>>(o0, o1, M, 512, 1024, 2048, 1024);
  }
  {
    LnJob a{F, PF,       ew[0][8], ew[0][9], X1b};
    LnJob b{F, PF + 512, ew[1][8], ew[1][9], X1b + 512};
    ln2_kernel<0><<<dim3(M,2),256,0,stream>>>(a, b, 512);
  }
  {
    GemmZ f0{X1b,       wtw1[0], ew[0][11], H1};
    GemmZ f1{X1b + 512, wtw1[1], ew[1][11], H1 + 2048};
    gemm256pz<1><<<dim3(40,8,2),512,0,stream>>>(f0, f1, M, 2048, 512, 1024, 4096);
  }
  {
    GemmZ f0{H1,        wtw2[0], ew[0][13], PF};
    GemmZ f1{H1 + 2048, wtw2[1], ew[1][13], PF + 512};
    gemm_btz<0,1><<<dim3(80,4,2),256,0,stream>>>(f0, f1, M, 512, 2048, 4096, 1024);
  }
  {
    LnJob a{X1b,       PF,       ew[0][14], ew[0][15], YC};
    LnJob b{X1b + 512, PF + 512, ew[1][14], ew[1][15], YC + 512};
    ln2_kernel<1><<<dim3(M,2),256,0,stream>>>(a, b, 1024);   // bf16 residual, stride 1024
  }

  // ---- fusion ----
  {
    GemmZ fz{YC, wtf1, fus_b1, Y1b};
    gemm_btz<0,1><<<dim3(80,4,1),256,0,stream>>>(fz, fz, M, 512, 1024, 1024, 512);
  }
  bn_part<<<256,512,0,stream>>>(Y1b, psum, psq);
  bn_fin<<<1,512,0,stream>>>(psum, psq, fus_bng, fus_bnb, bnsc, bnsh);
  bn_apply<<<5120,256,0,stream>>>(Y1b, bnsc, bnsh, Y2);
  {
    GemmZ fz{Y2, wtf2, fus_b2, d_out};
    gemm_btz<0,0><<<dim3(80,4,1),256,0,stream>>>(fz, fz, M, 512, 512, 512, 512);
  }
}